// Round 14
// baseline (198.566 us; speedup 1.0000x reference)
//
#include <hip/hip_runtime.h>

// GCN forward, MI355X. Dead MLP/adj branch skipped (unused in reference output).
// R14: perf round on the R9-passing structure (absmax 9.77e-4, 183us).
//   - gather: 8-deep neighbor unroll (32 uint4 loads in flight/wave, was 16); same add order
//     -> bit-identical sums.
//   - gemm: BM=32 x BN=64 tile, 2x4 micro-tile, grid 1024 blocks = 4 blocks/CU = 4 waves/SIMD
//     (was 512 blocks / 2 waves/SIMD); same k-order accumulation -> bit-identical.
//   5 kernels + memset; direct-load gather (no cross-lane index traffic - R5/R7 lesson).

#define NNODE 16384
#define NEDGE 524288
#define DIM   128
#define CAP   128        // bucket capacity; max in-degree ~60 for Binomial(E,1/N)
#define NMASK (NNODE - 1)

__device__ __forceinline__ float bflo(unsigned u) { return __uint_as_float(u << 16); }
__device__ __forceinline__ float bfhi(unsigned u) { return __uint_as_float(u & 0xFFFF0000u); }
__device__ __forceinline__ unsigned f2bf(float x) {            // RNE
    unsigned u = __float_as_uint(x);
    return (u + 0x7FFFu + ((u >> 16) & 1u)) >> 16;
}

// bucket fill: nbr16[c*CAP + cnt[c]++] = r
__global__ __launch_bounds__(256) void k_fill(const int* __restrict__ erow,
                                              const int* __restrict__ ecol,
                                              int* __restrict__ cnt,
                                              unsigned short* __restrict__ nbr) {
    int e = blockIdx.x * 256 + threadIdx.x;
    int r = erow[e] & NMASK;
    int c = ecol[e] & NMASK;
    int pos = atomicAdd(&cnt[c], 1) & (CAP - 1);
    nbr[(c << 7) + pos] = (unsigned short)r;
}

// lin16[r] = bf16( (A[r] @ W) * rsqrt(cnt[r]+1) ).
// 32x64 tile, 256 threads, 2x4 micro-tile; grid (512,2) = 1024 blocks = 4 blocks/CU.
__global__ __launch_bounds__(256) void k_gemm_scale(
    const float* __restrict__ A, const float* __restrict__ W,
    const int* __restrict__ cnt, unsigned short* __restrict__ lin)
{
    __shared__ float As[128][34];            // [k][row], pad 32->34 (2-way is free)
    const int tid  = threadIdx.x;
    const int row0 = blockIdx.x * 32;
    const int col0 = blockIdx.y * 64;

    #pragma unroll
    for (int it = 0; it < 16; ++it) {        // 32 rows x 128 k = 4096 floats, 16/thread
        int idx = it * 256 + tid;
        int r = idx >> 7, k = idx & 127;
        As[k][r] = A[(row0 + r) * DIM + k];
    }
    __syncthreads();

    const int tx = tid & 15, ty = tid >> 4;  // tx: 16 col-quads, ty: 16 row-pairs
    float acc[2][4] = {{0.f}};

    #pragma unroll 8
    for (int k = 0; k < 128; ++k) {
        float2 a = *(const float2*)&As[k][ty * 2];
        float4 w = *(const float4*)&W[k * DIM + col0 + tx * 4];
        acc[0][0] += a.x * w.x; acc[0][1] += a.x * w.y; acc[0][2] += a.x * w.z; acc[0][3] += a.x * w.w;
        acc[1][0] += a.y * w.x; acc[1][1] += a.y * w.y; acc[1][2] += a.y * w.z; acc[1][3] += a.y * w.w;
    }

    #pragma unroll
    for (int i = 0; i < 2; ++i) {
        int r = row0 + ty * 2 + i;
        float s = rsqrtf((float)(cnt[r] + 1));      // dinv, recomputed (no k_dinv kernel)
        unsigned p0 = f2bf(acc[i][0] * s) | (f2bf(acc[i][1] * s) << 16);
        unsigned p1 = f2bf(acc[i][2] * s) | (f2bf(acc[i][3] * s) << 16);
        *(uint2*)&lin[r * DIM + col0 + tx * 4] = make_uint2(p0, p1);
    }
}

// Wave-per-node gather (pre-scaled bf16 lin, pure fp32 sum). 4 groups x 16 lanes; lane owns
// 8 channels (uint4 of bf16x8). Group g handles slots j = g, g+4, ... via DIRECT nbr loads.
// 8-deep unroll: 8 independent uint4 loads in flight per group (32/wave).
// FINAL: also out10[node] = relu_x @ Wc + bc (grp0 -> cols 0..4, grp1 -> cols 5..9).
template<bool FINAL>
__global__ __launch_bounds__(256) void k_gather(
    const int* __restrict__ cnt, const unsigned short* __restrict__ nbr,
    const unsigned short* __restrict__ lin,
    const float* __restrict__ bias, float* __restrict__ out,
    const float* __restrict__ Wc, const float* __restrict__ bc,
    float* __restrict__ out10)
{
    __shared__ float Ws[FINAL ? DIM * 10 : 4];
    const int tid = threadIdx.x;
    if (FINAL) {
        for (int i = tid; i < DIM * 10; i += 256) Ws[i] = Wc[i];
        __syncthreads();
    }

    const int node = blockIdx.x * 4 + (tid >> 6);
    const int lane = tid & 63;
    const int grp  = lane >> 4;
    const int cl   = lane & 15;
    const int deg  = cnt[node];
    const float dn = rsqrtf((float)(deg + 1));
    const int  nb  = node << 7;

    float a[8] = {0.f,0.f,0.f,0.f,0.f,0.f,0.f,0.f};
    if (grp == 0) {  // self-loop (lin pre-scaled by dinv[node])
        uint4 u = *(const uint4*)&lin[(node << 7) + cl * 8];
        a[0] = bflo(u.x); a[1] = bfhi(u.x); a[2] = bflo(u.y); a[3] = bfhi(u.y);
        a[4] = bflo(u.z); a[5] = bfhi(u.z); a[6] = bflo(u.w); a[7] = bfhi(u.w);
    }

#define ACC1(u)                                   \
    a[0] += bflo(u.x); a[1] += bfhi(u.x);         \
    a[2] += bflo(u.y); a[3] += bfhi(u.y);         \
    a[4] += bflo(u.z); a[5] += bfhi(u.z);         \
    a[6] += bflo(u.w); a[7] += bfhi(u.w);

    int j = grp;
    for (; j + 28 < deg; j += 32) {       // 8 neighbors per group in flight
        int r0 = nbr[nb + j]      & NMASK;
        int r1 = nbr[nb + j + 4]  & NMASK;
        int r2 = nbr[nb + j + 8]  & NMASK;
        int r3 = nbr[nb + j + 12] & NMASK;
        int r4 = nbr[nb + j + 16] & NMASK;
        int r5 = nbr[nb + j + 20] & NMASK;
        int r6 = nbr[nb + j + 24] & NMASK;
        int r7 = nbr[nb + j + 28] & NMASK;
        uint4 u0 = *(const uint4*)&lin[(r0 << 7) + cl * 8];
        uint4 u1 = *(const uint4*)&lin[(r1 << 7) + cl * 8];
        uint4 u2 = *(const uint4*)&lin[(r2 << 7) + cl * 8];
        uint4 u3 = *(const uint4*)&lin[(r3 << 7) + cl * 8];
        uint4 u4 = *(const uint4*)&lin[(r4 << 7) + cl * 8];
        uint4 u5 = *(const uint4*)&lin[(r5 << 7) + cl * 8];
        uint4 u6 = *(const uint4*)&lin[(r6 << 7) + cl * 8];
        uint4 u7 = *(const uint4*)&lin[(r7 << 7) + cl * 8];
        ACC1(u0) ACC1(u1) ACC1(u2) ACC1(u3)
        ACC1(u4) ACC1(u5) ACC1(u6) ACC1(u7)
    }
    for (; j + 12 < deg; j += 16) {       // 4 in flight
        int r0 = nbr[nb + j]      & NMASK;
        int r1 = nbr[nb + j + 4]  & NMASK;
        int r2 = nbr[nb + j + 8]  & NMASK;
        int r3 = nbr[nb + j + 12] & NMASK;
        uint4 u0 = *(const uint4*)&lin[(r0 << 7) + cl * 8];
        uint4 u1 = *(const uint4*)&lin[(r1 << 7) + cl * 8];
        uint4 u2 = *(const uint4*)&lin[(r2 << 7) + cl * 8];
        uint4 u3 = *(const uint4*)&lin[(r3 << 7) + cl * 8];
        ACC1(u0) ACC1(u1) ACC1(u2) ACC1(u3)
    }
    for (; j < deg; j += 4) {
        int r = nbr[nb + j] & NMASK;
        uint4 u = *(const uint4*)&lin[(r << 7) + cl * 8];
        ACC1(u)
    }
#undef ACC1

    // full-wave reconvergence point; all 64 lanes active for the cross-group reduce
    #pragma unroll
    for (int k = 0; k < 8; ++k) {
        a[k] += __shfl_xor(a[k], 16);
        a[k] += __shfl_xor(a[k], 32);
    }

    const float4 b0 = *(const float4*)&bias[cl * 8];
    const float4 b1 = *(const float4*)&bias[cl * 8 + 4];
    a[0] = fmaxf(fmaf(a[0], dn, b0.x), 0.f);
    a[1] = fmaxf(fmaf(a[1], dn, b0.y), 0.f);
    a[2] = fmaxf(fmaf(a[2], dn, b0.z), 0.f);
    a[3] = fmaxf(fmaf(a[3], dn, b0.w), 0.f);
    a[4] = fmaxf(fmaf(a[4], dn, b1.x), 0.f);
    a[5] = fmaxf(fmaf(a[5], dn, b1.y), 0.f);
    a[6] = fmaxf(fmaf(a[6], dn, b1.z), 0.f);
    a[7] = fmaxf(fmaf(a[7], dn, b1.w), 0.f);

    if (grp == 0) *(float4*)&out[node * DIM + cl * 8]     = make_float4(a[0], a[1], a[2], a[3]);
    if (grp == 1) *(float4*)&out[node * DIM + cl * 8 + 4] = make_float4(a[4], a[5], a[6], a[7]);

    if (FINAL) {
        if (grp < 2) {
            // shfl_xor stays within the active 32-lane half (off<16) -> defined.
            const int jb = grp * 5;
            float s0 = 0.f, s1 = 0.f, s2 = 0.f, s3 = 0.f, s4 = 0.f;
            #pragma unroll
            for (int u = 0; u < 8; ++u) {
                const float xv = a[u];
                const float* wrow = &Ws[(cl * 8 + u) * 10 + jb];
                s0 = fmaf(xv, wrow[0], s0);
                s1 = fmaf(xv, wrow[1], s1);
                s2 = fmaf(xv, wrow[2], s2);
                s3 = fmaf(xv, wrow[3], s3);
                s4 = fmaf(xv, wrow[4], s4);
            }
            #pragma unroll
            for (int off = 1; off < 16; off <<= 1) {
                s0 += __shfl_xor(s0, off);
                s1 += __shfl_xor(s1, off);
                s2 += __shfl_xor(s2, off);
                s3 += __shfl_xor(s3, off);
                s4 += __shfl_xor(s4, off);
            }
            if (cl == 0) {
                float* o = &out10[node * 10 + jb];
                o[0] = s0 + bc[jb + 0];
                o[1] = s1 + bc[jb + 1];
                o[2] = s2 + bc[jb + 2];
                o[3] = s3 + bc[jb + 3];
                o[4] = s4 + bc[jb + 4];
            }
        }
    }
}

extern "C" void kernel_launch(void* const* d_in, const int* in_sizes, int n_in,
                              void* d_out, int out_size, void* d_ws, size_t ws_size,
                              hipStream_t stream)
{
    const float* fts  = (const float*)d_in[0];
    const int*   erow = (const int*)d_in[1];
    const int*   ecol = erow + NEDGE;
    const float* W_g1 = (const float*)d_in[6];
    const float* b_g1 = (const float*)d_in[7];
    const float* W_g2 = (const float*)d_in[8];
    const float* b_g2 = (const float*)d_in[9];
    const float* W_c  = (const float*)d_in[10];
    const float* b_c  = (const float*)d_in[11];

    float* out  = (float*)d_out;          // [16384,10]
    float* xout = out + NNODE * 10;       // [16384,128]

    int*            cnt   = (int*)d_ws;                       // 64 KB
    unsigned short* nbr16 = (unsigned short*)(cnt + NNODE);   // 4 MB
    unsigned short* lin16 = nbr16 + NNODE * CAP;              // 4 MB
    float*          bufB  = (float*)(lin16 + NNODE * DIM);    // 8 MB

    hipMemsetAsync(cnt, 0, NNODE * sizeof(int), stream);
    k_fill<<<NEDGE / 256, 256, 0, stream>>>(erow, ecol, cnt, nbr16);

    // conv1
    k_gemm_scale<<<dim3(NNODE / 32, 2), 256, 0, stream>>>(fts, W_g1, cnt, lin16);
    k_gather<false><<<NNODE / 4, 256, 0, stream>>>(cnt, nbr16, lin16, b_g1, bufB,
                                                   nullptr, nullptr, nullptr);
    // conv2 + fused final 128->10 GEMM
    k_gemm_scale<<<dim3(NNODE / 32, 2), 256, 0, stream>>>(bufB, W_g2, cnt, lin16);
    k_gather<true><<<NNODE / 4, 256, 0, stream>>>(cnt, nbr16, lin16, b_g2, xout,
                                                  W_c, b_c, out);
}

// Round 16
// 189.732 us; speedup vs baseline: 1.0466x; 1.0466x over previous
//
#include <hip/hip_runtime.h>

// GCN forward, MI355X. Dead MLP/adj branch skipped (unused in reference output).
// R15 (2nd submit; GPU-acquisition timeout, never benched): unbundle R14's regression
//     (183->198). Single change vs R14: GEMM reverted to the R9-proven 64x64 tile / 4x4
//     micro-tile (R14's 32x64 halved FMA:load ratio and doubled W re-reads). Gather keeps
//     the 8-deep unroll (the other R14 variable) for a clean A/B:
//     ~183 => unroll neutral & GEMM was the regression; <183 => unroll wins; ~198 => unroll hurts.

#define NNODE 16384
#define NEDGE 524288
#define DIM   128
#define CAP   128        // bucket capacity; max in-degree ~60 for Binomial(E,1/N)
#define NMASK (NNODE - 1)

__device__ __forceinline__ float bflo(unsigned u) { return __uint_as_float(u << 16); }
__device__ __forceinline__ float bfhi(unsigned u) { return __uint_as_float(u & 0xFFFF0000u); }
__device__ __forceinline__ unsigned f2bf(float x) {            // RNE
    unsigned u = __float_as_uint(x);
    return (u + 0x7FFFu + ((u >> 16) & 1u)) >> 16;
}

// bucket fill: nbr16[c*CAP + cnt[c]++] = r
__global__ __launch_bounds__(256) void k_fill(const int* __restrict__ erow,
                                              const int* __restrict__ ecol,
                                              int* __restrict__ cnt,
                                              unsigned short* __restrict__ nbr) {
    int e = blockIdx.x * 256 + threadIdx.x;
    int r = erow[e] & NMASK;
    int c = ecol[e] & NMASK;
    int pos = atomicAdd(&cnt[c], 1) & (CAP - 1);
    nbr[(c << 7) + pos] = (unsigned short)r;
}

// lin16[r] = bf16( (A[r] @ W) * rsqrt(cnt[r]+1) ). 64x64 tile, 256 threads, 4x4 micro-tile.
__global__ __launch_bounds__(256) void k_gemm_scale(
    const float* __restrict__ A, const float* __restrict__ W,
    const int* __restrict__ cnt, unsigned short* __restrict__ lin)
{
    __shared__ float As[128][68];
    const int tid  = threadIdx.x;
    const int row0 = blockIdx.x * 64;
    const int col0 = blockIdx.y * 64;

    #pragma unroll
    for (int it = 0; it < 32; ++it) {
        int idx = it * 256 + tid;
        int r = idx >> 7, k = idx & 127;
        As[k][r] = A[(row0 + r) * DIM + k];
    }
    __syncthreads();

    const int tx = tid & 15, ty = tid >> 4;
    float acc[4][4] = {{0.f}};

    #pragma unroll 8
    for (int k = 0; k < 128; ++k) {
        float4 a = *(const float4*)&As[k][ty * 4];
        float4 w = *(const float4*)&W[k * DIM + col0 + tx * 4];
        acc[0][0] += a.x * w.x; acc[0][1] += a.x * w.y; acc[0][2] += a.x * w.z; acc[0][3] += a.x * w.w;
        acc[1][0] += a.y * w.x; acc[1][1] += a.y * w.y; acc[1][2] += a.y * w.z; acc[1][3] += a.y * w.w;
        acc[2][0] += a.z * w.x; acc[2][1] += a.z * w.y; acc[2][2] += a.z * w.z; acc[2][3] += a.z * w.w;
        acc[3][0] += a.w * w.x; acc[3][1] += a.w * w.y; acc[3][2] += a.w * w.z; acc[3][3] += a.w * w.w;
    }

    #pragma unroll
    for (int i = 0; i < 4; ++i) {
        int r = row0 + ty * 4 + i;
        float s = rsqrtf((float)(cnt[r] + 1));      // dinv, recomputed (no k_dinv kernel)
        unsigned p0 = f2bf(acc[i][0] * s) | (f2bf(acc[i][1] * s) << 16);
        unsigned p1 = f2bf(acc[i][2] * s) | (f2bf(acc[i][3] * s) << 16);
        *(uint2*)&lin[r * DIM + col0 + tx * 4] = make_uint2(p0, p1);
    }
}

// Wave-per-node gather (pre-scaled bf16 lin, pure fp32 sum). 4 groups x 16 lanes; lane owns
// 8 channels (uint4 of bf16x8). Group g handles slots j = g, g+4, ... via DIRECT nbr loads.
// 8-deep unroll: 8 independent uint4 loads in flight per group (32/wave).
// FINAL: also out10[node] = relu_x @ Wc + bc (grp0 -> cols 0..4, grp1 -> cols 5..9).
template<bool FINAL>
__global__ __launch_bounds__(256) void k_gather(
    const int* __restrict__ cnt, const unsigned short* __restrict__ nbr,
    const unsigned short* __restrict__ lin,
    const float* __restrict__ bias, float* __restrict__ out,
    const float* __restrict__ Wc, const float* __restrict__ bc,
    float* __restrict__ out10)
{
    __shared__ float Ws[FINAL ? DIM * 10 : 4];
    const int tid = threadIdx.x;
    if (FINAL) {
        for (int i = tid; i < DIM * 10; i += 256) Ws[i] = Wc[i];
        __syncthreads();
    }

    const int node = blockIdx.x * 4 + (tid >> 6);
    const int lane = tid & 63;
    const int grp  = lane >> 4;
    const int cl   = lane & 15;
    const int deg  = cnt[node];
    const float dn = rsqrtf((float)(deg + 1));
    const int  nb  = node << 7;

    float a[8] = {0.f,0.f,0.f,0.f,0.f,0.f,0.f,0.f};
    if (grp == 0) {  // self-loop (lin pre-scaled by dinv[node])
        uint4 u = *(const uint4*)&lin[(node << 7) + cl * 8];
        a[0] = bflo(u.x); a[1] = bfhi(u.x); a[2] = bflo(u.y); a[3] = bfhi(u.y);
        a[4] = bflo(u.z); a[5] = bfhi(u.z); a[6] = bflo(u.w); a[7] = bfhi(u.w);
    }

#define ACC1(u)                                   \
    a[0] += bflo(u.x); a[1] += bfhi(u.x);         \
    a[2] += bflo(u.y); a[3] += bfhi(u.y);         \
    a[4] += bflo(u.z); a[5] += bfhi(u.z);         \
    a[6] += bflo(u.w); a[7] += bfhi(u.w);

    int j = grp;
    for (; j + 28 < deg; j += 32) {       // 8 neighbors per group in flight
        int r0 = nbr[nb + j]      & NMASK;
        int r1 = nbr[nb + j + 4]  & NMASK;
        int r2 = nbr[nb + j + 8]  & NMASK;
        int r3 = nbr[nb + j + 12] & NMASK;
        int r4 = nbr[nb + j + 16] & NMASK;
        int r5 = nbr[nb + j + 20] & NMASK;
        int r6 = nbr[nb + j + 24] & NMASK;
        int r7 = nbr[nb + j + 28] & NMASK;
        uint4 u0 = *(const uint4*)&lin[(r0 << 7) + cl * 8];
        uint4 u1 = *(const uint4*)&lin[(r1 << 7) + cl * 8];
        uint4 u2 = *(const uint4*)&lin[(r2 << 7) + cl * 8];
        uint4 u3 = *(const uint4*)&lin[(r3 << 7) + cl * 8];
        uint4 u4 = *(const uint4*)&lin[(r4 << 7) + cl * 8];
        uint4 u5 = *(const uint4*)&lin[(r5 << 7) + cl * 8];
        uint4 u6 = *(const uint4*)&lin[(r6 << 7) + cl * 8];
        uint4 u7 = *(const uint4*)&lin[(r7 << 7) + cl * 8];
        ACC1(u0) ACC1(u1) ACC1(u2) ACC1(u3)
        ACC1(u4) ACC1(u5) ACC1(u6) ACC1(u7)
    }
    for (; j + 12 < deg; j += 16) {       // 4 in flight
        int r0 = nbr[nb + j]      & NMASK;
        int r1 = nbr[nb + j + 4]  & NMASK;
        int r2 = nbr[nb + j + 8]  & NMASK;
        int r3 = nbr[nb + j + 12] & NMASK;
        uint4 u0 = *(const uint4*)&lin[(r0 << 7) + cl * 8];
        uint4 u1 = *(const uint4*)&lin[(r1 << 7) + cl * 8];
        uint4 u2 = *(const uint4*)&lin[(r2 << 7) + cl * 8];
        uint4 u3 = *(const uint4*)&lin[(r3 << 7) + cl * 8];
        ACC1(u0) ACC1(u1) ACC1(u2) ACC1(u3)
    }
    for (; j < deg; j += 4) {
        int r = nbr[nb + j] & NMASK;
        uint4 u = *(const uint4*)&lin[(r << 7) + cl * 8];
        ACC1(u)
    }
#undef ACC1

    // full-wave reconvergence point; all 64 lanes active for the cross-group reduce
    #pragma unroll
    for (int k = 0; k < 8; ++k) {
        a[k] += __shfl_xor(a[k], 16);
        a[k] += __shfl_xor(a[k], 32);
    }

    const float4 b0 = *(const float4*)&bias[cl * 8];
    const float4 b1 = *(const float4*)&bias[cl * 8 + 4];
    a[0] = fmaxf(fmaf(a[0], dn, b0.x), 0.f);
    a[1] = fmaxf(fmaf(a[1], dn, b0.y), 0.f);
    a[2] = fmaxf(fmaf(a[2], dn, b0.z), 0.f);
    a[3] = fmaxf(fmaf(a[3], dn, b0.w), 0.f);
    a[4] = fmaxf(fmaf(a[4], dn, b1.x), 0.f);
    a[5] = fmaxf(fmaf(a[5], dn, b1.y), 0.f);
    a[6] = fmaxf(fmaf(a[6], dn, b1.z), 0.f);
    a[7] = fmaxf(fmaf(a[7], dn, b1.w), 0.f);

    if (grp == 0) *(float4*)&out[node * DIM + cl * 8]     = make_float4(a[0], a[1], a[2], a[3]);
    if (grp == 1) *(float4*)&out[node * DIM + cl * 8 + 4] = make_float4(a[4], a[5], a[6], a[7]);

    if (FINAL) {
        if (grp < 2) {
            // shfl_xor stays within the active 32-lane half (off<16) -> defined.
            const int jb = grp * 5;
            float s0 = 0.f, s1 = 0.f, s2 = 0.f, s3 = 0.f, s4 = 0.f;
            #pragma unroll
            for (int u = 0; u < 8; ++u) {
                const float xv = a[u];
                const float* wrow = &Ws[(cl * 8 + u) * 10 + jb];
                s0 = fmaf(xv, wrow[0], s0);
                s1 = fmaf(xv, wrow[1], s1);
                s2 = fmaf(xv, wrow[2], s2);
                s3 = fmaf(xv, wrow[3], s3);
                s4 = fmaf(xv, wrow[4], s4);
            }
            #pragma unroll
            for (int off = 1; off < 16; off <<= 1) {
                s0 += __shfl_xor(s0, off);
                s1 += __shfl_xor(s1, off);
                s2 += __shfl_xor(s2, off);
                s3 += __shfl_xor(s3, off);
                s4 += __shfl_xor(s4, off);
            }
            if (cl == 0) {
                float* o = &out10[node * 10 + jb];
                o[0] = s0 + bc[jb + 0];
                o[1] = s1 + bc[jb + 1];
                o[2] = s2 + bc[jb + 2];
                o[3] = s3 + bc[jb + 3];
                o[4] = s4 + bc[jb + 4];
            }
        }
    }
}

extern "C" void kernel_launch(void* const* d_in, const int* in_sizes, int n_in,
                              void* d_out, int out_size, void* d_ws, size_t ws_size,
                              hipStream_t stream)
{
    const float* fts  = (const float*)d_in[0];
    const int*   erow = (const int*)d_in[1];
    const int*   ecol = erow + NEDGE;
    const float* W_g1 = (const float*)d_in[6];
    const float* b_g1 = (const float*)d_in[7];
    const float* W_g2 = (const float*)d_in[8];
    const float* b_g2 = (const float*)d_in[9];
    const float* W_c  = (const float*)d_in[10];
    const float* b_c  = (const float*)d_in[11];

    float* out  = (float*)d_out;          // [16384,10]
    float* xout = out + NNODE * 10;       // [16384,128]

    int*            cnt   = (int*)d_ws;                       // 64 KB
    unsigned short* nbr16 = (unsigned short*)(cnt + NNODE);   // 4 MB
    unsigned short* lin16 = nbr16 + NNODE * CAP;              // 4 MB
    float*          bufB  = (float*)(lin16 + NNODE * DIM);    // 8 MB

    hipMemsetAsync(cnt, 0, NNODE * sizeof(int), stream);
    k_fill<<<NEDGE / 256, 256, 0, stream>>>(erow, ecol, cnt, nbr16);

    // conv1
    k_gemm_scale<<<dim3(NNODE / 64, 2), 256, 0, stream>>>(fts, W_g1, cnt, lin16);
    k_gather<false><<<NNODE / 4, 256, 0, stream>>>(cnt, nbr16, lin16, b_g1, bufB,
                                                   nullptr, nullptr, nullptr);
    // conv2 + fused final 128->10 GEMM
    k_gemm_scale<<<dim3(NNODE / 64, 2), 256, 0, stream>>>(bufB, W_g2, cnt, lin16);
    k_gather<true><<<NNODE / 4, 256, 0, stream>>>(cnt, nbr16, lin16, b_g2, xout,
                                                  W_c, b_c, out);
}

// Round 17
// 179.283 us; speedup vs baseline: 1.1076x; 1.0583x over previous
//
#include <hip/hip_runtime.h>

// GCN forward, MI355X. Dead MLP/adj branch skipped (unused in reference output).
// R17: R9 anchor (183.4us; 4-deep gather REVERTED from the 8-deep that cost +6.3) with ONE
//     change: GEMM stages W in LDS (was: global float4 re-read 16x per block inside the
//     K-loop at only 2 waves/SIMD). Inner loop now pure LDS + FMA. Same FMA order ->
//     bit-identical output (absmax must stay exactly 0.0009765625).

#define NNODE 16384
#define NEDGE 524288
#define DIM   128
#define CAP   128        // bucket capacity; max in-degree ~60 for Binomial(E,1/N)
#define NMASK (NNODE - 1)

__device__ __forceinline__ float bflo(unsigned u) { return __uint_as_float(u << 16); }
__device__ __forceinline__ float bfhi(unsigned u) { return __uint_as_float(u & 0xFFFF0000u); }
__device__ __forceinline__ unsigned f2bf(float x) {            // RNE
    unsigned u = __float_as_uint(x);
    return (u + 0x7FFFu + ((u >> 16) & 1u)) >> 16;
}

// bucket fill: nbr16[c*CAP + cnt[c]++] = r
__global__ __launch_bounds__(256) void k_fill(const int* __restrict__ erow,
                                              const int* __restrict__ ecol,
                                              int* __restrict__ cnt,
                                              unsigned short* __restrict__ nbr) {
    int e = blockIdx.x * 256 + threadIdx.x;
    int r = erow[e] & NMASK;
    int c = ecol[e] & NMASK;
    int pos = atomicAdd(&cnt[c], 1) & (CAP - 1);
    nbr[(c << 7) + pos] = (unsigned short)r;
}

// lin16[r] = bf16( (A[r] @ W) * rsqrt(cnt[r]+1) ). 64x64 tile, 256 threads, 4x4 micro-tile.
// Both A (transposed) and W staged in LDS: 34816 + 32768 = 67.6 KB/block -> 2 blocks/CU.
// K-loop: 2 ds_read_b128 (broadcast / 2-way = conflict-free) + 16 FMA; no global latency.
__global__ __launch_bounds__(256) void k_gemm_scale(
    const float* __restrict__ A, const float* __restrict__ W,
    const int* __restrict__ cnt, unsigned short* __restrict__ lin)
{
    __shared__ float As[128][68];   // [k][row]
    __shared__ float Ws[128][64];   // [k][col]
    const int tid  = threadIdx.x;
    const int row0 = blockIdx.x * 64;
    const int col0 = blockIdx.y * 64;

    #pragma unroll
    for (int it = 0; it < 32; ++it) {        // A tile: 64 rows x 128 k, transposed
        int idx = it * 256 + tid;
        int r = idx >> 7, k = idx & 127;
        As[k][r] = A[(row0 + r) * DIM + k];
    }
    #pragma unroll
    for (int it = 0; it < 32; ++it) {        // W tile: 128 k x 64 cols, coalesced
        int idx = it * 256 + tid;
        int k = idx >> 6, c = idx & 63;
        Ws[k][c] = W[k * DIM + col0 + c];
    }
    __syncthreads();

    const int tx = tid & 15, ty = tid >> 4;
    float acc[4][4] = {{0.f}};

    #pragma unroll 8
    for (int k = 0; k < 128; ++k) {
        float4 a = *(const float4*)&As[k][ty * 4];
        float4 w = *(const float4*)&Ws[k][tx * 4];
        acc[0][0] += a.x * w.x; acc[0][1] += a.x * w.y; acc[0][2] += a.x * w.z; acc[0][3] += a.x * w.w;
        acc[1][0] += a.y * w.x; acc[1][1] += a.y * w.y; acc[1][2] += a.y * w.z; acc[1][3] += a.y * w.w;
        acc[2][0] += a.z * w.x; acc[2][1] += a.z * w.y; acc[2][2] += a.z * w.z; acc[2][3] += a.z * w.w;
        acc[3][0] += a.w * w.x; acc[3][1] += a.w * w.y; acc[3][2] += a.w * w.z; acc[3][3] += a.w * w.w;
    }

    #pragma unroll
    for (int i = 0; i < 4; ++i) {
        int r = row0 + ty * 4 + i;
        float s = rsqrtf((float)(cnt[r] + 1));      // dinv, recomputed (no k_dinv kernel)
        unsigned p0 = f2bf(acc[i][0] * s) | (f2bf(acc[i][1] * s) << 16);
        unsigned p1 = f2bf(acc[i][2] * s) | (f2bf(acc[i][3] * s) << 16);
        *(uint2*)&lin[r * DIM + col0 + tx * 4] = make_uint2(p0, p1);
    }
}

// Wave-per-node gather (pre-scaled bf16 lin, pure fp32 sum). 4 groups x 16 lanes; lane owns
// 8 channels (uint4 of bf16x8). Group g handles slots j = g, g+4, ... via DIRECT nbr loads
// (bucket = 1-2 L1 lines); 4-deep unroll (R9-proven; 8-deep cost +6.3us in R15).
// FINAL: also out10[node] = relu_x @ Wc + bc (grp0 -> cols 0..4, grp1 -> cols 5..9).
template<bool FINAL>
__global__ __launch_bounds__(256) void k_gather(
    const int* __restrict__ cnt, const unsigned short* __restrict__ nbr,
    const unsigned short* __restrict__ lin,
    const float* __restrict__ bias, float* __restrict__ out,
    const float* __restrict__ Wc, const float* __restrict__ bc,
    float* __restrict__ out10)
{
    __shared__ float Ws[FINAL ? DIM * 10 : 4];
    const int tid = threadIdx.x;
    if (FINAL) {
        for (int i = tid; i < DIM * 10; i += 256) Ws[i] = Wc[i];
        __syncthreads();
    }

    const int node = blockIdx.x * 4 + (tid >> 6);
    const int lane = tid & 63;
    const int grp  = lane >> 4;
    const int cl   = lane & 15;
    const int deg  = cnt[node];
    const float dn = rsqrtf((float)(deg + 1));
    const int  nb  = node << 7;

    float a[8] = {0.f,0.f,0.f,0.f,0.f,0.f,0.f,0.f};
    if (grp == 0) {  // self-loop (lin pre-scaled by dinv[node])
        uint4 u = *(const uint4*)&lin[(node << 7) + cl * 8];
        a[0] = bflo(u.x); a[1] = bfhi(u.x); a[2] = bflo(u.y); a[3] = bfhi(u.y);
        a[4] = bflo(u.z); a[5] = bfhi(u.z); a[6] = bflo(u.w); a[7] = bfhi(u.w);
    }

#define ACC1(u)                                   \
    a[0] += bflo(u.x); a[1] += bfhi(u.x);         \
    a[2] += bflo(u.y); a[3] += bfhi(u.y);         \
    a[4] += bflo(u.z); a[5] += bfhi(u.z);         \
    a[6] += bflo(u.w); a[7] += bfhi(u.w);

    int j = grp;
    for (; j + 12 < deg; j += 16) {       // 4 neighbors per group in flight
        int r0 = nbr[nb + j]      & NMASK;
        int r1 = nbr[nb + j + 4]  & NMASK;
        int r2 = nbr[nb + j + 8]  & NMASK;
        int r3 = nbr[nb + j + 12] & NMASK;
        uint4 u0 = *(const uint4*)&lin[(r0 << 7) + cl * 8];
        uint4 u1 = *(const uint4*)&lin[(r1 << 7) + cl * 8];
        uint4 u2 = *(const uint4*)&lin[(r2 << 7) + cl * 8];
        uint4 u3 = *(const uint4*)&lin[(r3 << 7) + cl * 8];
        ACC1(u0) ACC1(u1) ACC1(u2) ACC1(u3)
    }
    for (; j < deg; j += 4) {
        int r = nbr[nb + j] & NMASK;
        uint4 u = *(const uint4*)&lin[(r << 7) + cl * 8];
        ACC1(u)
    }
#undef ACC1

    // full-wave reconvergence point; all 64 lanes active for the cross-group reduce
    #pragma unroll
    for (int k = 0; k < 8; ++k) {
        a[k] += __shfl_xor(a[k], 16);
        a[k] += __shfl_xor(a[k], 32);
    }

    const float4 b0 = *(const float4*)&bias[cl * 8];
    const float4 b1 = *(const float4*)&bias[cl * 8 + 4];
    a[0] = fmaxf(fmaf(a[0], dn, b0.x), 0.f);
    a[1] = fmaxf(fmaf(a[1], dn, b0.y), 0.f);
    a[2] = fmaxf(fmaf(a[2], dn, b0.z), 0.f);
    a[3] = fmaxf(fmaf(a[3], dn, b0.w), 0.f);
    a[4] = fmaxf(fmaf(a[4], dn, b1.x), 0.f);
    a[5] = fmaxf(fmaf(a[5], dn, b1.y), 0.f);
    a[6] = fmaxf(fmaf(a[6], dn, b1.z), 0.f);
    a[7] = fmaxf(fmaf(a[7], dn, b1.w), 0.f);

    if (grp == 0) *(float4*)&out[node * DIM + cl * 8]     = make_float4(a[0], a[1], a[2], a[3]);
    if (grp == 1) *(float4*)&out[node * DIM + cl * 8 + 4] = make_float4(a[4], a[5], a[6], a[7]);

    if (FINAL) {
        if (grp < 2) {
            // shfl_xor stays within the active 32-lane half (off<16) -> defined.
            const int jb = grp * 5;
            float s0 = 0.f, s1 = 0.f, s2 = 0.f, s3 = 0.f, s4 = 0.f;
            #pragma unroll
            for (int u = 0; u < 8; ++u) {
                const float xv = a[u];
                const float* wrow = &Ws[(cl * 8 + u) * 10 + jb];
                s0 = fmaf(xv, wrow[0], s0);
                s1 = fmaf(xv, wrow[1], s1);
                s2 = fmaf(xv, wrow[2], s2);
                s3 = fmaf(xv, wrow[3], s3);
                s4 = fmaf(xv, wrow[4], s4);
            }
            #pragma unroll
            for (int off = 1; off < 16; off <<= 1) {
                s0 += __shfl_xor(s0, off);
                s1 += __shfl_xor(s1, off);
                s2 += __shfl_xor(s2, off);
                s3 += __shfl_xor(s3, off);
                s4 += __shfl_xor(s4, off);
            }
            if (cl == 0) {
                float* o = &out10[node * 10 + jb];
                o[0] = s0 + bc[jb + 0];
                o[1] = s1 + bc[jb + 1];
                o[2] = s2 + bc[jb + 2];
                o[3] = s3 + bc[jb + 3];
                o[4] = s4 + bc[jb + 4];
            }
        }
    }
}

extern "C" void kernel_launch(void* const* d_in, const int* in_sizes, int n_in,
                              void* d_out, int out_size, void* d_ws, size_t ws_size,
                              hipStream_t stream)
{
    const float* fts  = (const float*)d_in[0];
    const int*   erow = (const int*)d_in[1];
    const int*   ecol = erow + NEDGE;
    const float* W_g1 = (const float*)d_in[6];
    const float* b_g1 = (const float*)d_in[7];
    const float* W_g2 = (const float*)d_in[8];
    const float* b_g2 = (const float*)d_in[9];
    const float* W_c  = (const float*)d_in[10];
    const float* b_c  = (const float*)d_in[11];

    float* out  = (float*)d_out;          // [16384,10]
    float* xout = out + NNODE * 10;       // [16384,128]

    int*            cnt   = (int*)d_ws;                       // 64 KB
    unsigned short* nbr16 = (unsigned short*)(cnt + NNODE);   // 4 MB
    unsigned short* lin16 = nbr16 + NNODE * CAP;              // 4 MB
    float*          bufB  = (float*)(lin16 + NNODE * DIM);    // 8 MB

    hipMemsetAsync(cnt, 0, NNODE * sizeof(int), stream);
    k_fill<<<NEDGE / 256, 256, 0, stream>>>(erow, ecol, cnt, nbr16);

    // conv1
    k_gemm_scale<<<dim3(NNODE / 64, 2), 256, 0, stream>>>(fts, W_g1, cnt, lin16);
    k_gather<false><<<NNODE / 4, 256, 0, stream>>>(cnt, nbr16, lin16, b_g1, bufB,
                                                   nullptr, nullptr, nullptr);
    // conv2 + fused final 128->10 GEMM
    k_gemm_scale<<<dim3(NNODE / 64, 2), 256, 0, stream>>>(bufB, W_g2, cnt, lin16);
    k_gather<true><<<NNODE / 4, 256, 0, stream>>>(cnt, nbr16, lin16, b_g2, xout,
                                                  W_c, b_c, out);
}